// Round 3
// baseline (321.791 us; speedup 1.0000x reference)
//
#include <hip/hip_runtime.h>

// StationLoss: B=16, H=W=2048, S=5000, KERNEL_SIZE=3, METRIC=MSE
// Theory-B attack: the scattered 3x3 gather is DRAM row-miss throughput-bound
// (Round-2 evidence: 4x occupancy, 1/3 loads/thread -> identical time).
// Fix: counting-sort stations by (b, py>>3, px>>10) so consecutive threads
// gather from the same ~64KB window (one DRAM row-buffer span at 256B channel
// interleave) -> row hits instead of row misses.
// Pipeline: zero hist -> histogram -> scan -> scatter packed records ->
//           sorted gather + block reduce -> final reduce.

#define BB 16
#define HH 2048
#define WW 2048
#define SS 5000
#define NSTATIONS (BB * SS)                 // 80000
#define THREADS 256
#define NB_STATION ((NSTATIONS + THREADS - 1) / THREADS)  // 313
#define NBUCKETS 8192                       // 16 b * 256 y-bands * 2 x-halves

// ws layout (bytes):
//   [0,     32768)  u32  hist[NBUCKETS]
//   [32768, 36864)  f32  partials[NB_STATION] (padded)
//   [36864, ...  )  uint2 sorted[NSTATIONS]  (8B records, 640 KB)

__device__ __forceinline__ int bucket_of(int b, int px, int py) {
    return (b << 9) | ((py >> 3) << 1) | (px >> 10);
}

__global__ __launch_bounds__(THREADS) void zero_hist(unsigned int* __restrict__ hist) {
    int t = blockIdx.x * blockDim.x + threadIdx.x;
    if (t < NBUCKETS) hist[t] = 0u;
}

__global__ __launch_bounds__(THREADS) void hist_kernel(
    const int2* __restrict__ pos, unsigned int* __restrict__ hist)
{
    int t = blockIdx.x * blockDim.x + threadIdx.x;
    if (t < NSTATIONS) {
        int b = t / SS;
        int2 p = pos[t];                    // coalesced
        atomicAdd(&hist[bucket_of(b, p.x, p.y)], 1u);
    }
}

__global__ __launch_bounds__(1024) void scan_kernel(unsigned int* __restrict__ hist)
{
    __shared__ unsigned int sums[1024];
    int t = threadIdx.x;
    unsigned int local[8];
    unsigned int s = 0;
    #pragma unroll
    for (int i = 0; i < 8; ++i) { local[i] = hist[t * 8 + i]; s += local[i]; }
    sums[t] = s;
    __syncthreads();
    // Hillis-Steele inclusive scan over 1024 thread-sums
    for (int off = 1; off < 1024; off <<= 1) {
        unsigned int v = (t >= off) ? sums[t - off] : 0u;
        __syncthreads();
        sums[t] += v;
        __syncthreads();
    }
    unsigned int base = sums[t] - s;        // exclusive prefix for this thread
    #pragma unroll
    for (int i = 0; i < 8; ++i) {
        unsigned int c = local[i];
        hist[t * 8 + i] = base;             // hist becomes atomic cursors
        base += c;
    }
}

__global__ __launch_bounds__(THREADS) void scatter_kernel(
    const int2* __restrict__ pos, const float* __restrict__ runoff,
    unsigned int* __restrict__ hist, uint2* __restrict__ sorted)
{
    int t = blockIdx.x * blockDim.x + threadIdx.x;
    if (t < NSTATIONS) {
        int b = t / SS;
        int2 p = pos[t];                    // coalesced
        float r = runoff[t];                // coalesced
        unsigned int idx = atomicAdd(&hist[bucket_of(b, p.x, p.y)], 1u);
        // pack: px (11b) | py<<11 (11b) | b<<22 (4b)
        unsigned int packed = (unsigned int)p.x | ((unsigned int)p.y << 11)
                            | ((unsigned int)b << 22);
        sorted[idx] = make_uint2(packed, __float_as_uint(r));  // scattered 8B, L2-absorbed
    }
}

__global__ __launch_bounds__(THREADS) void gather_kernel(
    const float* __restrict__ pred, const uint2* __restrict__ sorted,
    float* __restrict__ partials)
{
    int t = blockIdx.x * blockDim.x + threadIdx.x;
    float contrib = 0.0f;
    if (t < NSTATIONS) {
        uint2 rec = sorted[t];              // coalesced
        int px = (int)(rec.x & 2047u);
        int py = (int)((rec.x >> 11) & 2047u);
        int b  = (int)(rec.x >> 22);
        float ro = __uint_as_float(rec.y);
        const float* img = pred + (size_t)b * (size_t)(HH * WW);

        float sum = 0.0f;
        float cnt = 0.0f;
        #pragma unroll
        for (int dy = -1; dy <= 1; ++dy) {
            int y = py + dy;
            bool yok = (y >= 0) & (y < HH);
            int yc = min(max(y, 0), HH - 1);
            const float* row = img + (size_t)yc * WW;
            #pragma unroll
            for (int dx = -1; dx <= 1; ++dx) {
                int x = px + dx;
                bool ok = yok & (x >= 0) & (x < WW);
                int xc = min(max(x, 0), WW - 1);
                float v = row[xc];          // clamped -> in-bounds
                float m = ok ? 1.0f : 0.0f;
                sum += v * m;
                cnt += m;
            }
        }
        float avg = sum / cnt;              // cnt >= 4 always
        float d = avg - ro;
        contrib = d * d;
    }

    #pragma unroll
    for (int off = 32; off > 0; off >>= 1)
        contrib += __shfl_down(contrib, off, 64);

    __shared__ float waves[THREADS / 64];
    int lane = threadIdx.x & 63;
    int wid  = threadIdx.x >> 6;
    if (lane == 0) waves[wid] = contrib;
    __syncthreads();
    if (threadIdx.x == 0) {
        float s = 0.0f;
        #pragma unroll
        for (int i = 0; i < THREADS / 64; ++i) s += waves[i];
        partials[blockIdx.x] = s;
    }
}

__global__ __launch_bounds__(512) void reduce_kernel(
    const float* __restrict__ partials, float* __restrict__ out)
{
    float v = 0.0f;
    for (int i = threadIdx.x; i < NB_STATION; i += 512) v += partials[i];
    #pragma unroll
    for (int off = 32; off > 0; off >>= 1)
        v += __shfl_down(v, off, 64);

    __shared__ float waves[512 / 64];
    int lane = threadIdx.x & 63;
    int wid  = threadIdx.x >> 6;
    if (lane == 0) waves[wid] = v;
    __syncthreads();
    if (threadIdx.x == 0) {
        float s = 0.0f;
        #pragma unroll
        for (int i = 0; i < 512 / 64; ++i) s += waves[i];
        out[0] = s * (1.0f / (float)NSTATIONS);
    }
}

extern "C" void kernel_launch(void* const* d_in, const int* in_sizes, int n_in,
                              void* d_out, int out_size, void* d_ws, size_t ws_size,
                              hipStream_t stream) {
    const float* pred   = (const float*)d_in[0];
    const int2*  pos    = (const int2*)d_in[1];
    const float* runoff = (const float*)d_in[2];
    float* out = (float*)d_out;

    char* ws = (char*)d_ws;
    unsigned int* hist  = (unsigned int*)(ws);
    float* partials     = (float*)(ws + 32768);
    uint2* sorted       = (uint2*)(ws + 36864);

    zero_hist<<<NBUCKETS / THREADS, THREADS, 0, stream>>>(hist);
    hist_kernel<<<NB_STATION, THREADS, 0, stream>>>(pos, hist);
    scan_kernel<<<1, 1024, 0, stream>>>(hist);
    scatter_kernel<<<NB_STATION, THREADS, 0, stream>>>(pos, runoff, hist, sorted);
    gather_kernel<<<NB_STATION, THREADS, 0, stream>>>(pred, sorted, partials);
    reduce_kernel<<<1, 512, 0, stream>>>(partials, out);
}

// Round 4
// 306.157 us; speedup vs baseline: 1.0511x; 1.0511x over previous
//
#include <hip/hip_runtime.h>

// StationLoss: B=16, H=W=2048, S=5000, KERNEL_SIZE=3, METRIC=MSE
// Best-measured structure (306.7 us): minimal 2-launch pipeline.
// The timed window is dominated by harness poison fills (~165us @ 80% HBM
// peak, rocprof top-5); kernel side responds only to launch count.
//   4 lanes per station (one 3-wide window ROW per lane, lane 3 idle),
//   320k threads / 1250 blocks. Row partials combined via 2x shfl_xor.
// Kernel 2 reduces the 1250 block partials to the scalar mean.

#define BB 16
#define HH 2048
#define WW 2048
#define SS 5000
#define NSTATIONS (BB * SS)            // 80000
#define LPS 4                          // lanes per station (3 active + 1 idle)
#define NTHREADS_TOTAL (NSTATIONS * LPS)  // 320000
#define THREADS 256
#define NBLOCKS (NTHREADS_TOTAL / THREADS)  // 1250 exactly

__global__ __launch_bounds__(THREADS) void station_partial_kernel(
    const float* __restrict__ pred,       // (B,1,H,W)
    const int2*  __restrict__ pos,        // (B,S,2) -> {px, py}
    const float* __restrict__ runoff,     // (B,S)
    float* __restrict__ partials)         // (NBLOCKS,)
{
    int t = blockIdx.x * blockDim.x + threadIdx.x;
    int s = t >> 2;                       // station index [0, NSTATIONS)
    int r = t & 3;                        // window row 0..2, r==3 idle

    float sum = 0.0f;
    float cnt = 0.0f;
    if (r < 3) {
        int b = s / SS;
        int2 p = pos[s];                  // p.x = px (width), p.y = py (height)
        int px = p.x;
        int py = p.y;

        int y = py + (r - 1);
        bool yok = (y >= 0) & (y < HH);
        int yc = min(max(y, 0), HH - 1);
        const float* row = pred + (size_t)b * (size_t)(HH * WW) + (size_t)yc * WW;

        #pragma unroll
        for (int dx = -1; dx <= 1; ++dx) {
            int x = px + dx;
            bool ok = yok & (x >= 0) & (x < WW);
            int xc = min(max(x, 0), WW - 1);
            float v = row[xc];            // clamped -> always in-bounds
            float m = ok ? 1.0f : 0.0f;
            sum += v * m;
            cnt += m;
        }
    }

    // combine the 3 row-partials within each 4-lane group (xor 1, xor 2)
    sum += __shfl_xor(sum, 1, 64);
    sum += __shfl_xor(sum, 2, 64);
    cnt += __shfl_xor(cnt, 1, 64);
    cnt += __shfl_xor(cnt, 2, 64);

    float contrib = 0.0f;
    if (r == 0) {
        float avg = sum / cnt;            // cnt >= 4 always
        float d = avg - runoff[s];        // runoff gathered by 1 lane per station
        contrib = d * d;
    }

    // wave-64 reduction (non-r0 lanes contribute 0)
    #pragma unroll
    for (int off = 32; off > 0; off >>= 1)
        contrib += __shfl_down(contrib, off, 64);

    __shared__ float waves[THREADS / 64];
    int lane = threadIdx.x & 63;
    int wid  = threadIdx.x >> 6;
    if (lane == 0) waves[wid] = contrib;
    __syncthreads();
    if (threadIdx.x == 0) {
        float blk = 0.0f;
        #pragma unroll
        for (int i = 0; i < THREADS / 64; ++i) blk += waves[i];
        partials[blockIdx.x] = blk;
    }
}

__global__ __launch_bounds__(512) void reduce_kernel(
    const float* __restrict__ partials, float* __restrict__ out)
{
    float v = 0.0f;
    for (int i = threadIdx.x; i < NBLOCKS; i += 512) v += partials[i];
    #pragma unroll
    for (int off = 32; off > 0; off >>= 1)
        v += __shfl_down(v, off, 64);

    __shared__ float waves[512 / 64];
    int lane = threadIdx.x & 63;
    int wid  = threadIdx.x >> 6;
    if (lane == 0) waves[wid] = v;
    __syncthreads();
    if (threadIdx.x == 0) {
        float s = 0.0f;
        #pragma unroll
        for (int i = 0; i < 512 / 64; ++i) s += waves[i];
        out[0] = s * (1.0f / (float)NSTATIONS);
    }
}

extern "C" void kernel_launch(void* const* d_in, const int* in_sizes, int n_in,
                              void* d_out, int out_size, void* d_ws, size_t ws_size,
                              hipStream_t stream) {
    const float* pred   = (const float*)d_in[0];
    const int2*  pos    = (const int2*)d_in[1];
    const float* runoff = (const float*)d_in[2];
    float* out      = (float*)d_out;
    float* partials = (float*)d_ws;

    station_partial_kernel<<<NBLOCKS, THREADS, 0, stream>>>(pred, pos, runoff, partials);
    reduce_kernel<<<1, 512, 0, stream>>>(partials, out);
}